// Round 7
// baseline (180.081 us; speedup 1.0000x reference)
//
#include <hip/hip_runtime.h>
#include <math.h>

#define NROW 4096
#define NDIM 128
#define KNN 10
#define LDSS 136  // bf16 LDS row stride (128 + 8 pad), 16B aligned

typedef __bf16 bf16x8 __attribute__((ext_vector_type(8)));
typedef unsigned short u16x8 __attribute__((ext_vector_type(8)));
typedef float f32x4 __attribute__((ext_vector_type(4)));

__device__ inline unsigned short f2bf(float f) {  // RTNE f32->bf16
    unsigned int u = __float_as_uint(f);
    u += 0x7FFFu + ((u >> 16) & 1u);
    return (unsigned short)(u >> 16);
}
__device__ inline float bf2f(unsigned short u) {
    return __uint_as_float((unsigned)u << 16);
}
__device__ inline unsigned fmap(float f) {
    unsigned b = __float_as_uint(f);
    return b ^ ((b >> 31) ? 0xFFFFFFFFu : 0x80000000u);
}
__device__ inline float funmap(unsigned u) {
    unsigned b = (u & 0x80000000u) ? (u ^ 0x80000000u) : ~u;
    return __uint_as_float(b);
}

// Layouts:
//  - Dx intermediate (bf16): tail half of each f32 P-row slot
//      (u16*)(P + i*NROW + NROW/2), 4096 u16 = 8 KB per row.
//  - Mb (bf16 masked matrix, 1 MB): FRONT half of P rows 0..127.
//      row r, col c -> (u16*)(P + (r>>5)*NROW) [ (r&31)*NDIM + c ]
//    (front halves are dead space until k_norm overwrites; k_dx only writes
//     tail halves, so reads/writes are disjoint.)
//  - ws (small): r f32[4096] @0 | knn f32[4096] @4096 | scale @8192 |
//                hist u32[4096] @ (float)8320
__device__ inline unsigned short* mb_ptr(float* P, int row) {
    return (unsigned short*)(P + (size_t)(row >> 5) * NROW) + (row & 31) * NDIM;
}

// --- K1: gate, masked(f32) + bf16 copy into P-front, r = rowsum(m^2),
//         zero hist[row] ----------------------------------------------------
__global__ __launch_bounds__(128) void k_mask(const float* __restrict__ x,
                                              const float* __restrict__ alpha,
                                              const float* __restrict__ noise,
                                              float* __restrict__ masked,
                                              float* __restrict__ P,
                                              float* __restrict__ r,
                                              unsigned* __restrict__ hist) {
    int row = blockIdx.x;
    int c = threadIdx.x;
    if (c == 0) hist[row] = 0u;
    float g = alpha[c] + 0.5f * noise[c] + 0.5f;
    g = fminf(fmaxf(g, 0.0f), 1.0f);
    float m = x[row * NDIM + c] * g;
    masked[row * NDIM + c] = m;
    mb_ptr(P, row)[c] = f2bf(m);
    float v = m * m;
#pragma unroll
    for (int o = 32; o > 0; o >>= 1) v += __shfl_down(v, o, 64);
    __shared__ float partial[2];
    if ((c & 63) == 0) partial[c >> 6] = v;
    __syncthreads();
    if (c == 0) r[row] = partial[0] + partial[1];
}

// --- K2: Dx = r_i + r_j - 2*M M^T via bf16 MFMA; stages bf16 (pure copy) ----
__global__ __launch_bounds__(256) void k_dx(float* __restrict__ P,
                                            const float* __restrict__ r) {
    __shared__ __align__(16) __bf16 Asm[128 * LDSS];
    __shared__ __align__(16) __bf16 Bsm[128 * LDSS];
    int tid = threadIdx.x;
    int bx = blockIdx.x, by = blockIdx.y;

    {
        int c = (tid & 15) * 8;
        int r0 = tid >> 4;
#pragma unroll
        for (int i = 0; i < 8; ++i) {
            int row = r0 + i * 16;
            *(u16x8*)&Asm[row * LDSS + c] =
                *(const u16x8*)(mb_ptr(P, by * 128 + row) + c);
            *(u16x8*)&Bsm[row * LDSS + c] =
                *(const u16x8*)(mb_ptr(P, bx * 128 + row) + c);
        }
    }
    __syncthreads();

    int wave = tid >> 6, lane = tid & 63;
    int wr = wave >> 1, wc = wave & 1;
    int quad = lane >> 4, l15 = lane & 15;

    f32x4 acc[4][4];
#pragma unroll
    for (int i = 0; i < 4; ++i)
#pragma unroll
        for (int j = 0; j < 4; ++j) acc[i][j] = (f32x4)(0.0f);

#pragma unroll
    for (int kk = 0; kk < 128; kk += 32) {
        int ka = kk + quad * 8;
        bf16x8 af[4], bfr[4];
#pragma unroll
        for (int ti = 0; ti < 4; ++ti)
            af[ti] = *(const bf16x8*)&Asm[(wr * 64 + ti * 16 + l15) * LDSS + ka];
#pragma unroll
        for (int tj = 0; tj < 4; ++tj)
            bfr[tj] = *(const bf16x8*)&Bsm[(wc * 64 + tj * 16 + l15) * LDSS + ka];
#pragma unroll
        for (int ti = 0; ti < 4; ++ti)
#pragma unroll
            for (int tj = 0; tj < 4; ++tj)
                acc[ti][tj] = __builtin_amdgcn_mfma_f32_16x16x32_bf16(
                    af[ti], bfr[tj], acc[ti][tj], 0, 0, 0);
    }

    int gi_base = by * 128 + wr * 64;
    int gj_base = bx * 128 + wc * 64;
    float rrow[4][4], rcol[4];
#pragma unroll
    for (int ti = 0; ti < 4; ++ti)
#pragma unroll
        for (int rg = 0; rg < 4; ++rg)
            rrow[ti][rg] = r[gi_base + ti * 16 + quad * 4 + rg];
#pragma unroll
    for (int tj = 0; tj < 4; ++tj) rcol[tj] = r[gj_base + tj * 16 + l15];
#pragma unroll
    for (int ti = 0; ti < 4; ++ti)
#pragma unroll
        for (int rg = 0; rg < 4; ++rg) {
            int grow = gi_base + ti * 16 + quad * 4 + rg;
            unsigned short* brow =
                (unsigned short*)(P + (size_t)grow * NROW + NROW / 2);
#pragma unroll
            for (int tj = 0; tj < 4; ++tj) {
                int gcol = gj_base + tj * 16 + l15;
                float d = rrow[ti][rg] + rcol[tj] - 2.0f * acc[ti][tj][rg];
                brow[gcol] = f2bf(d);
            }
        }
}

// --- K3: wave-per-row register top-10 + shuffle merge; coarse hist atomic ----
__global__ __launch_bounds__(256) void k_knn(const float* __restrict__ P,
                                             float* __restrict__ knn,
                                             unsigned* __restrict__ hist) {
    int tid = threadIdx.x;
    int wave = tid >> 6, lane = tid & 63;
    int row = blockIdx.x * 4 + wave;
    const unsigned short* drow =
        (const unsigned short*)(P + (size_t)row * NROW + NROW / 2);

    float t[KNN];
#pragma unroll
    for (int j = 0; j < KNN; ++j) t[j] = INFINITY;

#pragma unroll
    for (int c = 0; c < 8; ++c) {
        u16x8 v8 = *(const u16x8*)(drow + (c * 64 + lane) * 8);
#pragma unroll
        for (int e = 0; e < 8; ++e) {
            float cv = bf2f(v8[e]);
#pragma unroll
            for (int j = 0; j < KNN; ++j) {
                float lo = fminf(t[j], cv);
                cv = fmaxf(t[j], cv);
                t[j] = lo;
            }
        }
    }

#pragma unroll
    for (int r = 0; r < KNN; ++r) {
        float v = t[0];
        int src = lane;
#pragma unroll
        for (int o = 1; o < 64; o <<= 1) {
            float ov = __shfl_xor(v, o, 64);
            int osrc = __shfl_xor(src, o, 64);
            if (ov < v || (ov == v && osrc < src)) { v = ov; src = osrc; }
        }
        if (r == KNN - 1) {
            if (lane == 0) {
                knn[row] = v;
                atomicAdd(&hist[fmap(v) >> 20], 1u);  // 12-bit coarse bin
            }
        } else if (src == lane) {
#pragma unroll
            for (int j = 0; j < KNN - 1; ++j) t[j] = t[j + 1];
            t[KNN - 1] = INFINITY;
        }
    }
}

// --- K4: median from coarse hist (free) + 2x10-bit radix refine --------------
__global__ __launch_bounds__(1024) void k_sigma(const float* __restrict__ knn,
                                                const unsigned* __restrict__ hist,
                                                float* __restrict__ scale_out) {
    __shared__ unsigned keys[NROW];
    __shared__ unsigned h2[1024];
    __shared__ unsigned wsum[16], woff[16];
    __shared__ unsigned s_prefix, s_R;
    __shared__ float red_f[16];
    __shared__ unsigned red_u[16];
    int tid = threadIdx.x;
    int lane = tid & 63, wid = tid >> 6;

#pragma unroll
    for (int l = 0; l < 4; ++l) keys[tid + l * 1024] = fmap(knn[tid + l * 1024]);

    // coarse round from precomputed histogram: find 12-bit bin of rank 2047
    unsigned b[4];
    unsigned lsum = 0;
#pragma unroll
    for (int j = 0; j < 4; ++j) {
        b[j] = hist[tid * 4 + j];
        lsum += b[j];
    }
    unsigned pfx = lsum;
#pragma unroll
    for (int o = 1; o < 64; o <<= 1) {
        unsigned v = __shfl_up(pfx, o, 64);
        if (lane >= o) pfx += v;
    }
    if (lane == 63) wsum[wid] = pfx;
    __syncthreads();
    if (tid == 0) {
        unsigned acc = 0;
        for (int i = 0; i < 16; ++i) {
            woff[i] = acc;
            acc += wsum[i];
        }
    }
    __syncthreads();
    unsigned excl = woff[wid] + pfx - lsum;
    unsigned R0 = 2047;
    if (R0 >= excl && R0 < excl + lsum) {
        unsigned cum = excl;
#pragma unroll
        for (int j = 0; j < 4; ++j) {
            if (R0 < cum + b[j]) {
                s_prefix = tid * 4 + j;
                s_R = R0 - cum;
                break;
            }
            cum += b[j];
        }
    }
    __syncthreads();

    // 2 refine rounds over bits [10,20) then [0,10)
#pragma unroll 1
    for (int rd = 0; rd < 2; ++rd) {
        int sh = (rd == 0) ? 10 : 0;
        h2[tid] = 0;
        __syncthreads();
        unsigned prefix = s_prefix;
        unsigned R = s_R;
        int hsh = sh + 10;
#pragma unroll
        for (int l = 0; l < 4; ++l) {
            unsigned k = keys[tid + l * 1024];
            if ((k >> hsh) == prefix) atomicAdd(&h2[(k >> sh) & 1023u], 1u);
        }
        __syncthreads();
        if (tid < 64) {
            unsigned base = tid * 16;
            unsigned ls = 0;
            for (int i = 0; i < 16; ++i) ls += h2[base + i];
            unsigned p2 = ls;
#pragma unroll
            for (int o = 1; o < 64; o <<= 1) {
                unsigned v = __shfl_up(p2, o, 64);
                if (tid >= o) p2 += v;
            }
            unsigned ex = p2 - ls;
            if (R >= ex && R < ex + ls) {
                unsigned cum = ex;
                for (int i = 0; i < 16; ++i) {
                    unsigned h = h2[base + i];
                    if (R < cum + h) {
                        s_prefix = (prefix << 10) | (base + i);
                        s_R = R - cum;
                        break;
                    }
                    cum += h;
                }
            }
        }
        __syncthreads();
    }

    unsigned mlk = s_prefix;  // full 32-bit key of rank-2047
    unsigned cnt = 0, mng = 0xFFFFFFFFu;
#pragma unroll
    for (int l = 0; l < 4; ++l) {
        unsigned k = keys[tid + l * 1024];
        if (k <= mlk) cnt++;
        else mng = min(mng, k);
    }
#pragma unroll
    for (int o = 32; o > 0; o >>= 1) {
        cnt += __shfl_down(cnt, o, 64);
        mng = min(mng, (unsigned)__shfl_down(mng, o, 64));
    }
    if (lane == 0) { red_u[wid] = cnt; red_f[wid] = __uint_as_float(mng); }
    __syncthreads();
    if (tid == 0) {
        unsigned ctot = 0, m = 0xFFFFFFFFu;
        for (int w = 0; w < 16; ++w) {
            ctot += red_u[w];
            m = min(m, __float_as_uint(red_f[w]));
        }
        float ml = funmap(mlk);
        float mu = (ctot >= 2049u) ? ml : funmap(m);
        float sigma = 0.5f * (mu + ml);
        if (sigma < 1e-8f) sigma = 1.0f;
        scale_out[0] = -1.0f / (2.0f * sigma);
    }
}

// --- K5: P-row = exp(bf16Dx*scale)/rowsum, reads own tail, f32 out ----------
__global__ __launch_bounds__(256) void k_norm(float* __restrict__ P,
                                              const float* __restrict__ scale_p) {
    int row = blockIdx.x, tid = threadIdx.x;
    float scale = scale_p[0];
    float* drow = P + (size_t)row * NROW;
    const unsigned short* brow = (const unsigned short*)(drow + NROW / 2);

    u16x8 a = *(const u16x8*)(brow + tid * 16);
    u16x8 bq = *(const u16x8*)(brow + tid * 16 + 8);
    float v[16];
#pragma unroll
    for (int e = 0; e < 8; ++e) v[e] = __expf(bf2f(a[e]) * scale);
#pragma unroll
    for (int e = 0; e < 8; ++e) v[8 + e] = __expf(bf2f(bq[e]) * scale);
    float sum = 0.0f;
#pragma unroll
    for (int e = 0; e < 16; ++e) sum += v[e];
#pragma unroll
    for (int o = 32; o > 0; o >>= 1) sum += __shfl_down(sum, o, 64);
    __shared__ float ps[4];
    int lane = tid & 63, wid = tid >> 6;
    if (lane == 0) ps[wid] = sum;
    __syncthreads();  // also orders all bf16 reads before the f32 overwrite
    float inv = 1.0f / (ps[0] + ps[1] + ps[2] + ps[3]);
#pragma unroll
    for (int l = 0; l < 4; ++l) {
        float4 o4;
        o4.x = v[l * 4 + 0] * inv;
        o4.y = v[l * 4 + 1] * inv;
        o4.z = v[l * 4 + 2] * inv;
        o4.w = v[l * 4 + 3] * inv;
        *(float4*)(drow + tid * 16 + l * 4) = o4;
    }
}

extern "C" void kernel_launch(void* const* d_in, const int* in_sizes, int n_in,
                              void* d_out, int out_size, void* d_ws, size_t ws_size,
                              hipStream_t stream) {
    const float* x = (const float*)d_in[0];
    const float* alpha = (const float*)d_in[1];
    const float* noise = (const float*)d_in[2];
    float* out = (float*)d_out;
    float* P = out;
    float* masked = out + (size_t)NROW * NROW;
    float* ws = (float*)d_ws;
    float* r = ws;                                       // f32[4096]
    float* knn = ws + NROW;                              // f32[4096]
    float* scale = ws + 2 * NROW;                        // f32[1]
    unsigned* hist = (unsigned*)(ws + 2 * NROW + 128);   // u32[4096]

    k_mask<<<NROW, 128, 0, stream>>>(x, alpha, noise, masked, P, r, hist);
    k_dx<<<dim3(NROW / 128, NROW / 128), 256, 0, stream>>>(P, r);
    k_knn<<<NROW / 4, 256, 0, stream>>>(P, knn, hist);
    k_sigma<<<1, 1024, 0, stream>>>(knn, hist, scale);
    k_norm<<<NROW, 256, 0, stream>>>(P, scale);
}